// Round 1
// baseline (4465.875 us; speedup 1.0000x reference)
//
#include <hip/hip_runtime.h>
#include <cstdint>

#define NUM_CLASSES 20
#define KSEL 5
#define M_PTS 10000
#define C_DIM 256
#define HW 16384
#define NQ_BLK 128
#define BJ 256
#define BK 32
#define BSP 260      // Bs row pad: 260 floats = 1040 B = 65*16 -> b128-aligned rows, odd bank phase
#define NLIST 5
#define NJT 40       // 40*256 = 10240 >= 10000

// Block: 128 queries x (all M). 256 threads, micro-tile 8 rows x 16 cols.
__global__ __launch_bounds__(256, 1) void knn_kernel(
    const float* __restrict__ x,
    const float* __restrict__ mx,
    const int* __restrict__ my,
    float* __restrict__ out)
{
  __shared__ __align__(16) float As[BK][128];   // 16 KB  [c][query]
  __shared__ __align__(16) float Bs[BK][BSP];   // 33.3 KB [c][mem j] (transposed in LDS)
  __shared__ float mnS[BJ];                     // 1 KB
  __shared__ float Lv[NQ_BLK * 16 * NLIST];     // 40 KB  per-(row, tj) top-5 scores
  __shared__ int   Lj[NQ_BLK * 16 * NLIST];     // 40 KB  per-(row, tj) top-5 indices

  const int t   = threadIdx.x;
  const int ti  = t & 15;        // row group: queries ti*8 .. ti*8+7
  const int tj  = t >> 4;        // col group: j tj*16 .. tj*16+15
  const int i0  = blockIdx.x * NQ_BLK;
  const int bb  = i0 >> 14;                 // batch (HW = 16384)
  const int hw0 = i0 & (HW - 1);
  const float* xbase = x + (size_t)bb * C_DIM * HW + hw0;  // element [c][q] at c*HW + q

  // init per-(row,tj) lists (each thread owns its 8 rows at column tj -> race-free)
  #pragma unroll
  for (int r = 0; r < 8; ++r) {
    const int lb = ((ti * 8 + r) * 16 + tj) * NLIST;
    #pragma unroll
    for (int e = 0; e < NLIST; ++e) { Lv[lb + e] = 1e30f; Lj[lb + e] = 0x7fffffff; }
  }
  float thr[8];
  #pragma unroll
  for (int r = 0; r < 8; ++r) thr[r] = 1e30f;

  const int a_row = t >> 3, a_seg = t & 7;   // As staging: 32 rows x 8 threads/row
  const int b_c4  = t & 7,  b_jj  = t >> 3;  // Bs staging: 8 c-quads x 32 j, 8 reps

  for (int jt = 0; jt < NJT; ++jt) {
    const int j0 = jt * BJ;
    __syncthreads();   // previous tile's selection (mnS readers) done

    // per-tile ||m||^2 (recomputed per block; ~1% of FMA cost, avoids d_ws use)
    {
      const int j  = j0 + t;
      const int gr = (j < M_PTS) ? j : (M_PTS - 1);
      const float4* row = (const float4*)(mx + (size_t)gr * C_DIM);
      float s = 0.f;
      #pragma unroll 8
      for (int k2 = 0; k2 < C_DIM / 4; ++k2) {
        float4 v = row[k2];
        s = fmaf(v.x, v.x, s); s = fmaf(v.y, v.y, s);
        s = fmaf(v.z, v.z, s); s = fmaf(v.w, v.w, s);
      }
      mnS[t] = (j < M_PTS) ? s : 1e30f;
    }

    float acc[8][16];
    #pragma unroll
    for (int r = 0; r < 8; ++r)
      #pragma unroll
      for (int s = 0; s < 16; ++s) acc[r][s] = 0.f;

    for (int ckt = 0; ckt < C_DIM / BK; ++ckt) {
      const int c0 = ckt * BK;
      // prefetch globals into regs BEFORE the barrier (latency overlaps barrier skew)
      const float* gA = xbase + (size_t)(c0 + a_row) * HW + a_seg * 4;
      float4 va0 = *(const float4*)(gA);
      float4 va1 = *(const float4*)(gA + 32);
      float4 va2 = *(const float4*)(gA + 64);
      float4 va3 = *(const float4*)(gA + 96);
      float4 vb[8];
      #pragma unroll
      for (int rep = 0; rep < 8; ++rep) {
        int jl = b_jj + rep * 32;
        int grow = j0 + jl; grow = (grow < M_PTS) ? grow : (M_PTS - 1);
        vb[rep] = *(const float4*)(mx + (size_t)grow * C_DIM + c0 + b_c4 * 4);
      }
      __syncthreads();   // previous tile's LDS readers done
      *(float4*)&As[a_row][a_seg * 4]      = va0;
      *(float4*)&As[a_row][a_seg * 4 + 32] = va1;
      *(float4*)&As[a_row][a_seg * 4 + 64] = va2;
      *(float4*)&As[a_row][a_seg * 4 + 96] = va3;
      #pragma unroll
      for (int rep = 0; rep < 8; ++rep) {
        int jl = b_jj + rep * 32;
        Bs[b_c4 * 4 + 0][jl] = vb[rep].x;
        Bs[b_c4 * 4 + 1][jl] = vb[rep].y;
        Bs[b_c4 * 4 + 2][jl] = vb[rep].z;
        Bs[b_c4 * 4 + 3][jl] = vb[rep].w;
      }
      __syncthreads();

      #pragma unroll 8
      for (int ck = 0; ck < BK; ++ck) {
        float4 a0 = *(const float4*)&As[ck][ti * 8];
        float4 a1 = *(const float4*)&As[ck][ti * 8 + 4];
        float4 b0 = *(const float4*)&Bs[ck][tj * 16];
        float4 b1 = *(const float4*)&Bs[ck][tj * 16 + 4];
        float4 b2 = *(const float4*)&Bs[ck][tj * 16 + 8];
        float4 b3 = *(const float4*)&Bs[ck][tj * 16 + 12];
        const float av[8]  = {a0.x, a0.y, a0.z, a0.w, a1.x, a1.y, a1.z, a1.w};
        const float bv2[16] = {b0.x, b0.y, b0.z, b0.w, b1.x, b1.y, b1.z, b1.w,
                               b2.x, b2.y, b2.z, b2.w, b3.x, b3.y, b3.z, b3.w};
        #pragma unroll
        for (int r = 0; r < 8; ++r)
          #pragma unroll
          for (int s = 0; s < 16; ++s)
            acc[r][s] = fmaf(av[r], bv2[s], acc[r][s]);
      }
    }

    // selection: score = ||m||^2 - 2*dot (||x||^2 is rank-invariant per query).
    // candidates arrive in increasing j, so strict '<' == top_k's lower-index tie-break.
    float mnr[16];
    #pragma unroll
    for (int s = 0; s < 16; ++s) mnr[s] = mnS[tj * 16 + s];
    #pragma unroll
    for (int r = 0; r < 8; ++r) {
      float th = thr[r];
      const int lb = ((ti * 8 + r) * 16 + tj) * NLIST;
      #pragma unroll
      for (int s = 0; s < 16; ++s) {
        const float sc = fmaf(-2.f, acc[r][s], mnr[s]);
        if (sc < th) {
          const int jidx = j0 + tj * 16 + s;
          int p = NLIST - 1;
          while (p > 0 && Lv[lb + p - 1] > sc) {
            Lv[lb + p] = Lv[lb + p - 1]; Lj[lb + p] = Lj[lb + p - 1]; --p;
          }
          Lv[lb + p] = sc; Lj[lb + p] = jidx;
          th = Lv[lb + NLIST - 1];
        }
      }
      thr[r] = th;
    }
  }

  __syncthreads();
  if (t < NQ_BLK) {     // one thread per query: merge, fp64-refine, vote, write
    // merge 16 partial top-5 lists -> fp32 top-8 superset (tie: smaller j first)
    float bv[8]; int bj2[8];
    #pragma unroll
    for (int k2 = 0; k2 < 8; ++k2) { bv[k2] = 1e30f; bj2[k2] = 0x7fffffff; }
    for (int p = 0; p < 16; ++p) {
      #pragma unroll
      for (int e = 0; e < NLIST; ++e) {
        const float v = Lv[(t * 16 + p) * NLIST + e];
        const int  j = Lj[(t * 16 + p) * NLIST + e];
        if (v < bv[7] || (v == bv[7] && j < bj2[7])) {
          int pos = 7;
          while (pos > 0 && (bv[pos - 1] > v || (bv[pos - 1] == v && bj2[pos - 1] > j))) {
            bv[pos] = bv[pos - 1]; bj2[pos] = bj2[pos - 1]; --pos;
          }
          bv[pos] = v; bj2[pos] = j;
        }
      }
    }
    // fp64 exact distances for the 8 candidates (x reads coalesced across lanes)
    const int j_0 = bj2[0], j_1 = bj2[1], j_2 = bj2[2], j_3 = bj2[3];
    const int j_4 = bj2[4], j_5 = bj2[5], j_6 = bj2[6], j_7 = bj2[7];
    const float *m0 = mx + (size_t)j_0 * C_DIM, *m1 = mx + (size_t)j_1 * C_DIM;
    const float *m2 = mx + (size_t)j_2 * C_DIM, *m3 = mx + (size_t)j_3 * C_DIM;
    const float *m4 = mx + (size_t)j_4 * C_DIM, *m5 = mx + (size_t)j_5 * C_DIM;
    const float *m6 = mx + (size_t)j_6 * C_DIM, *m7 = mx + (size_t)j_7 * C_DIM;
    double d0 = 0, d1 = 0, d2 = 0, d3 = 0, d4 = 0, d5 = 0, d6 = 0, d7 = 0;
    for (int c = 0; c < C_DIM; ++c) {
      const double xv = (double)xbase[(size_t)c * HW + t];
      double dd;
      dd = xv - (double)m0[c]; d0 = fma(dd, dd, d0);
      dd = xv - (double)m1[c]; d1 = fma(dd, dd, d1);
      dd = xv - (double)m2[c]; d2 = fma(dd, dd, d2);
      dd = xv - (double)m3[c]; d3 = fma(dd, dd, d3);
      dd = xv - (double)m4[c]; d4 = fma(dd, dd, d4);
      dd = xv - (double)m5[c]; d5 = fma(dd, dd, d5);
      dd = xv - (double)m6[c]; d6 = fma(dd, dd, d6);
      dd = xv - (double)m7[c]; d7 = fma(dd, dd, d7);
    }
    const double dv[8] = {d0, d1, d2, d3, d4, d5, d6, d7};
    const int    jv[8] = {j_0, j_1, j_2, j_3, j_4, j_5, j_6, j_7};
    int lab[KSEL];
    unsigned used = 0;
    #pragma unroll
    for (int n = 0; n < KSEL; ++n) {
      double bd = 1e300; int bjx = 0x7fffffff; int bk = 0;
      #pragma unroll
      for (int k2 = 0; k2 < 8; ++k2) {
        const bool avail = ((used >> k2) & 1u) == 0u;
        if (avail && (dv[k2] < bd || (dv[k2] == bd && jv[k2] < bjx))) {
          bd = dv[k2]; bjx = jv[k2]; bk = k2;
        }
      }
      used |= (1u << bk);
      lab[n] = my[bjx];
    }
    // mode vote; tie -> smallest class id (matches one_hot-sum + argmax)
    int bestLab = NUM_CLASSES; int bestCnt = 0;
    #pragma unroll
    for (int a = 0; a < KSEL; ++a) {
      const int la = lab[a];
      int cnt = 0;
      #pragma unroll
      for (int b2 = 0; b2 < KSEL; ++b2) cnt += (lab[b2] == la) ? 1 : 0;
      if (cnt > bestCnt || (cnt == bestCnt && la < bestLab)) { bestCnt = cnt; bestLab = la; }
    }
    // one-hot write, coalesced per class plane
    float* obase = out + (size_t)bb * NUM_CLASSES * HW + hw0 + t;
    #pragma unroll
    for (int cls = 0; cls < NUM_CLASSES; ++cls)
      obase[(size_t)cls * HW] = (cls == bestLab) ? 1.0f : 0.0f;
  }
}

extern "C" void kernel_launch(void* const* d_in, const int* in_sizes, int n_in,
                              void* d_out, int out_size, void* d_ws, size_t ws_size,
                              hipStream_t stream) {
  (void)in_sizes; (void)n_in; (void)d_ws; (void)ws_size; (void)out_size;
  const float* x  = (const float*)d_in[0];
  // d_in[1] (y) is unused by the reference
  const float* mx = (const float*)d_in[2];
  const int*   my = (const int*)d_in[3];
  float* out = (float*)d_out;
  knn_kernel<<<256, 256, 0, stream>>>(x, mx, my, out);
}